// Round 2
// baseline (349.520 us; speedup 1.0000x reference)
//
#include <hip/hip_runtime.h>

// FlattenHead: compact valid rows of x[B,T,D] (fp32) into out, where row (b,t)
// is valid iff t < seq_lens[b]. out[pfx[b]+t, :] = x[b, t, :].
// Pure memory-bound row gather: ~268 MB traffic -> ~43 us floor at 6.3 TB/s.
//
// Single kernel: every block recomputes the 17-entry exclusive scan of
// seq_lens (B=16, broadcast cache-hit loads, fully unrolled, static register
// indexing) -- removes the serialized prefix dispatch and the d_ws dependency.

#define DD 1024   // floats per row
#define TT 4096   // rows per batch
#define NB 16     // batch count (fixed by problem)

__global__ __launch_bounds__(256) void gather_rows(
        const float4* __restrict__ x, const void* __restrict__ seq_raw,
        float4* __restrict__ out, int total_rows) {
    // --- per-thread uniform prefix scan of seq_lens -------------------------
    // Dtype defense: reference says int64; harness doc says int*. Pick the
    // interpretation whose total matches total_rows (= out_size / D).
    const int*       s32 = (const int*)seq_raw;
    const long long* s64 = (const long long*)seq_raw;
    long long sum32 = 0;
#pragma unroll
    for (int i = 0; i < NB; ++i) sum32 += (long long)s32[i];
    const bool use32 = (sum32 == (long long)total_rows);

    int pfx[NB + 1];
    pfx[0] = 0;
#pragma unroll
    for (int i = 0; i < NB; ++i)
        pfx[i + 1] = pfx[i] + (use32 ? s32[i] : (int)s64[i]);

    // --- grid-stride copy over float4 elements ------------------------------
    // j indexes the output as float4[total_rows * 256]; r = output row.
    const int n4     = total_rows << 8;            // 256 float4 per row
    const int stride = gridDim.x * blockDim.x;
    for (int j = blockIdx.x * blockDim.x + threadIdx.x; j < n4; j += stride) {
        const int r = j >> 8;
        // b = largest batch with pfx[b] <= r; base = pfx[b]. Static indexing
        // only (cndmask chain) -- no scratch spill.
        int b = 0, base = 0;
#pragma unroll
        for (int i = 1; i <= NB; ++i) {
            const bool c = (pfx[i] <= r);
            b   += c;
            base = c ? pfx[i] : base;
        }
        const int t = r - base;
        out[j] = x[(((size_t)b * TT + (size_t)t) << 8) + (size_t)(j & 255)];
    }
}

extern "C" void kernel_launch(void* const* d_in, const int* in_sizes, int n_in,
                              void* d_out, int out_size, void* d_ws, size_t ws_size,
                              hipStream_t stream) {
    const float4* x   = (const float4*)d_in[0];
    const void*   seq = d_in[1];
    float4*       out = (float4*)d_out;

    const int total_rows = out_size / DD;
    if (total_rows <= 0) return;

    const int n4     = total_rows << 8;
    int       blocks = (n4 + 255) / 256;
    if (blocks > 2048) blocks = 2048;              // ~8 blocks/CU, grid-stride
    gather_rows<<<blocks, 256, 0, stream>>>(x, seq, out, total_rows);
}